// Round 4
// baseline (305.438 us; speedup 1.0000x reference)
//
#include <hip/hip_runtime.h>

typedef unsigned short u16;
typedef unsigned int   u32;

typedef short shortx8  __attribute__((ext_vector_type(8)));
typedef float floatx4  __attribute__((ext_vector_type(4)));
typedef u32   uintx4   __attribute__((ext_vector_type(4)));

typedef u32     u32a     __attribute__((may_alias));
typedef uintx4  uintx4a  __attribute__((may_alias));
typedef shortx8 shortx8a __attribute__((may_alias));

__device__ __forceinline__ u16 f2bf(float f){
  union { float f; u32 i; } v; v.f = f;
  return (u16)((v.i + 0x7fffu + ((v.i >> 16) & 1u)) >> 16);
}
// Diagnostic clamp: never binds on correct values (|v| <~ 10)
__device__ __forceinline__ float clampv(float v){
  return fminf(fmaxf(v, -1.0e4f), 1.0e4f);
}

// ---------------------------------------------------------------------------
// Kernel A: fp32 -> bf16 cast (grid-stride)
// ---------------------------------------------------------------------------
__global__ void __launch_bounds__(256) cvt_bf16(const float* __restrict__ src,
                                                u16* __restrict__ dst, int n){
  for (int i = blockIdx.x*256 + threadIdx.x; i < n; i += gridDim.x*256)
    dst[i] = f2bf(src[i]);
}

// ---------------------------------------------------------------------------
// Kernel 0: pad gcn_w [256][1908] fp32 -> [256][1920] bf16 (zero tail cols)
// ---------------------------------------------------------------------------
__global__ void __launch_bounds__(256) pad_gcnw(const float* __restrict__ gw,
                                                u16* __restrict__ gwp){
  const int row = blockIdx.x;
  for (int col = threadIdx.x; col < 1920; col += 256)
    gwp[row*1920 + col] = (col < 1908) ? f2bf(gw[row*1908 + col]) : (u16)0;
}

// ---------------------------------------------------------------------------
// Kernel 1: fused conv1 (fp32 VALU) -> conv2 -> conv3 (MFMA 16x16x32 bf16,
// m89/m91/m120-verified mappings). Inputs fp32; LDS intermediates bf16.
// grid (32 t-tiles, 16 b-groups, 15 nodes), block 256.
// ---------------------------------------------------------------------------
__global__ void __launch_bounds__(256) fused_conv(
    const float* __restrict__ X,
    const float* __restrict__ w1, const float* __restrict__ b1,
    const float* __restrict__ w2, const float* __restrict__ b2,
    const float* __restrict__ w3, const float* __restrict__ b3,
    u16* __restrict__ h3p){
  const int tid  = threadIdx.x;
  const int node = blockIdx.z;
  const int p    = blockIdx.x * 60;
  const int b0   = blockIdx.y * 8;

  __shared__ __attribute__((aligned(16))) u16 sH1[8*68*24]; // [b][t68][ic16+pad]
  __shared__ __attribute__((aligned(16))) u16 sH2[4*68*40]; // per-wave [t68][ic32+pad]
  __shared__ __attribute__((aligned(16))) u16 sW2[2560];    // [oc32][ic16][tap5] bf16
  __shared__ __attribute__((aligned(16))) u16 sW3[160];     // [tap][ic32] bf16
  __shared__ float sX[8*76];
  __shared__ float sW1[80];
  __shared__ float sB1[16];
  __shared__ float sB2[32];

  // ---- stage X window + params (fp32 loads, bf16 weight casts) ----
  {
    const int bls = tid >> 5, i0 = tid & 31;
    const float* xrow = X + (size_t)((b0 + bls)*15 + node)*1920;
    #pragma unroll
    for (int u = 0; u < 3; ++u){
      int i = i0 + 32*u;
      if (i < 72){
        int g = p + i;
        sX[bls*76 + i] = (g < 1920) ? xrow[g] : 0.f;
      }
    }
    for (int i = tid; i < 2560; i += 256) sW2[i] = f2bf(w2[node*2560 + i]);
    if (tid < 160){
      int ic = tid / 5, tp = tid - 5*ic;
      sW3[tp*32 + ic] = f2bf(w3[node*160 + tid]);
      #pragma unroll
      for (int ww = 0; ww < 4; ++ww) sH2[ww*2720 + 2560 + tid] = 0;
    }
    if (tid < 80) sW1[tid] = w1[node*80 + tid];
    if (tid < 16) sB1[tid] = b1[node*16 + tid];
    if (tid < 32) sB2[tid] = b2[node*32 + tid];
  }
  __syncthreads();

  // ---- conv1 (VALU): 32 threads/batch, each 2 ic x 17 t ----
  {
    const int bls = tid >> 5, sub = tid & 31;
    const int ic = (sub & 7)*2, th = sub >> 3;
    float wa[5], wb[5];
    #pragma unroll
    for (int k = 0; k < 5; ++k){ wa[k] = sW1[ic*5+k]; wb[k] = sW1[ic*5+5+k]; }
    const float ba = sB1[ic], bbv = sB1[ic+1];
    const float* xr = sX + bls*76;
    const int t0 = th*17;
    float x0 = xr[t0], x1 = xr[t0+1], x2 = xr[t0+2], x3 = xr[t0+3];
    u16* h1w = sH1 + bls*1632 + ic;
    for (int i = 0; i < 17; ++i){
      float x4 = xr[t0+i+4];
      float va = ba  + wa[0]*x0 + wa[1]*x1 + wa[2]*x2 + wa[3]*x3 + wa[4]*x4;
      float vb = bbv + wb[0]*x0 + wb[1]*x1 + wb[2]*x2 + wb[3]*x3 + wb[4]*x4;
      va = va > 0.f ? va : 0.01f*va;
      vb = vb > 0.f ? vb : 0.01f*vb;
      *(u32a*)(h1w + (t0+i)*24) = (u32)f2bf(va) | ((u32)f2bf(vb) << 16);
      x0 = x1; x1 = x2; x2 = x3; x3 = x4;
    }
  }
  __syncthreads();

  // ---- conv2 + conv3 (per wave, 2 batches each), barrier-separated ----
  const int w = tid >> 6, lane = tid & 63;
  const int m = lane & 15, quad = lane >> 4;
  const int icb = (quad & 1)*8;   // ic base within k
  const int tpo = quad >> 1;      // tap offset within pair

  // conv2 A-frags: element j -> k=quad*8+j -> (ic=icb+j, tap=2*pi+tpo); tap5 zero
  shortx8 a2[2][3];
  #pragma unroll
  for (int o = 0; o < 2; ++o)
    #pragma unroll
    for (int pi = 0; pi < 3; ++pi){
      const int tap = 2*pi + tpo;
      #pragma unroll
      for (int j = 0; j < 8; ++j)
        a2[o][pi][j] = (tap < 5) ? (short)sW2[((o*16 + m)*16 + icb + j)*5 + tap]
                                 : (short)0;
    }
  float biasr2[2][4];
  #pragma unroll
  for (int o = 0; o < 2; ++o)
    #pragma unroll
    for (int r = 0; r < 4; ++r)
      biasr2[o][r] = sB2[o*16 + quad*4 + r];

  // conv3 A-frags: only row m=0 nonzero; element j -> k = ic = quad*8+j
  shortx8 a3[5];
  #pragma unroll
  for (int tp = 0; tp < 5; ++tp)
    #pragma unroll
    for (int j = 0; j < 8; ++j)
      a3[tp][j] = (m == 0) ? (short)sW3[tp*32 + quad*8 + j] : (short)0;

  const float b3v = b3[node];
  u16* h2w = sH2 + w*2720;

  for (int bb = 0; bb < 2; ++bb){
    const int bl = w + bb*4;
    const u16* h1b = sH1 + bl*1632;

    // -- conv2: 2 oc-halves x 4 t-tiles, 3 tap-pair MFMAs each --
    #pragma unroll
    for (int o = 0; o < 2; ++o){
      #pragma unroll
      for (int q = 0; q < 4; ++q){
        floatx4 acc = {0.f, 0.f, 0.f, 0.f};
        const int trow = q*16 + m;
        #pragma unroll
        for (int pi = 0; pi < 3; ++pi){
          const int row = trow + 2*pi + ((pi < 2) ? tpo : 0);
          shortx8 bfr = *(const shortx8a*)(h1b + row*24 + icb);
          acc = __builtin_amdgcn_mfma_f32_16x16x32_bf16(a2[o][pi], bfr, acc, 0, 0, 0);
        }
        #pragma unroll
        for (int r = 0; r < 4; r += 2){
          float v0 = acc[r]   + biasr2[o][r];
          float v1 = acc[r+1] + biasr2[o][r+1];
          v0 = v0 > 0.f ? v0 : 0.01f*v0;
          v1 = v1 > 0.f ? v1 : 0.01f*v1;
          v0 = clampv(v0); v1 = clampv(v1);
          const int oc0 = o*16 + quad*4 + r;
          *(u32a*)(h2w + trow*40 + oc0) = (u32)f2bf(v0) | ((u32)f2bf(v1) << 16);
        }
      }
    }
    __syncthreads();

    // -- conv3: 4 t-tiles, 5 tap MFMAs (K=32=ic); result in D row 0 --
    const int rg = (b0 + bl)*15 + node;
    #pragma unroll
    for (int nt = 0; nt < 4; ++nt){
      floatx4 acc3;
      acc3[0] = (lane < 16) ? b3v : 0.f;
      acc3[1] = 0.f; acc3[2] = 0.f; acc3[3] = 0.f;
      #pragma unroll
      for (int tp = 0; tp < 5; ++tp){
        shortx8 bfr = *(const shortx8a*)(h2w + (nt*16 + m + tp)*40 + quad*8);
        acc3 = __builtin_amdgcn_mfma_f32_16x16x32_bf16(a3[tp], bfr, acc3, 0, 0, 0);
      }
      const int tl = nt*16 + lane;
      if (lane < 16 && tl < 60){
        const int t3 = p + tl;
        if (t3 < 1920){
          float v = acc3[0];
          v = v > 0.f ? v : 0.01f*v;
          v = clampv(v);
          h3p[(size_t)rg*1920 + t3] = (t3 < 1908) ? f2bf(v) : (u16)0;
        }
      }
    }
    __syncthreads();
  }
}

// ---------------------------------------------------------------------------
// Kernel 2: NT GEMM  O[1920][256] = A[1920][1920] * B[256][1920]^T (bf16->fp32)
// z=0: A=Xb, B=lwb, O=l1;  z=1: A=h3p, B=gwp, O=xl
// ---------------------------------------------------------------------------
__global__ void __launch_bounds__(256) gemm_nt(
    const u16* __restrict__ A0, const u16* __restrict__ B0, float* __restrict__ O0,
    const u16* __restrict__ A1, const u16* __restrict__ B1, float* __restrict__ O1){
  const u16* A; const u16* Bm; float* O;
  if (blockIdx.z == 0){ A = A0; Bm = B0; O = O0; } else { A = A1; Bm = B1; O = O1; }
  __shared__ __attribute__((aligned(16))) u16 sA[64*40];
  __shared__ __attribute__((aligned(16))) u16 sB[64*40];
  const int tid = threadIdx.x;
  const int m0 = blockIdx.x*64, n0 = blockIdx.y*64;
  const int row = tid >> 2, kc = tid & 3;
  const int w = tid >> 6, lane = tid & 63;
  const int mo = (w & 1)*32, no = (w >> 1)*32;
  floatx4 acc[2][2];
  #pragma unroll
  for (int i = 0; i < 2; ++i)
    #pragma unroll
    for (int j = 0; j < 2; ++j)
      #pragma unroll
      for (int r = 0; r < 4; ++r) acc[i][j][r] = 0.f;

  const u16* ap = A  + (size_t)(m0 + row)*1920 + kc*8;
  const u16* bp = Bm + (size_t)(n0 + row)*1920 + kc*8;
  for (int kt = 0; kt < 60; ++kt){
    uintx4 va = *(const uintx4a*)ap;
    uintx4 vb = *(const uintx4a*)bp;
    ap += 32; bp += 32;
    *(uintx4a*)&sA[row*40 + kc*8] = va;
    *(uintx4a*)&sB[row*40 + kc*8] = vb;
    __syncthreads();
    const shortx8 af0 = *(const shortx8a*)&sA[(mo      + (lane & 15))*40 + (lane >> 4)*8];
    const shortx8 af1 = *(const shortx8a*)&sA[(mo + 16 + (lane & 15))*40 + (lane >> 4)*8];
    const shortx8 bf0 = *(const shortx8a*)&sB[(no      + (lane & 15))*40 + (lane >> 4)*8];
    const shortx8 bf1 = *(const shortx8a*)&sB[(no + 16 + (lane & 15))*40 + (lane >> 4)*8];
    acc[0][0] = __builtin_amdgcn_mfma_f32_16x16x32_bf16(af0, bf0, acc[0][0], 0, 0, 0);
    acc[0][1] = __builtin_amdgcn_mfma_f32_16x16x32_bf16(af0, bf1, acc[0][1], 0, 0, 0);
    acc[1][0] = __builtin_amdgcn_mfma_f32_16x16x32_bf16(af1, bf0, acc[1][0], 0, 0, 0);
    acc[1][1] = __builtin_amdgcn_mfma_f32_16x16x32_bf16(af1, bf1, acc[1][1], 0, 0, 0);
    __syncthreads();
  }
  #pragma unroll
  for (int mi = 0; mi < 2; ++mi)
    #pragma unroll
    for (int ni = 0; ni < 2; ++ni)
      #pragma unroll
      for (int r = 0; r < 4; ++r){
        int rr = m0 + mo + mi*16 + (lane >> 4)*4 + r;
        int cc = n0 + no + ni*16 + (lane & 15);
        O[(size_t)rr*256 + cc] = clampv(acc[mi][ni][r]);
      }
}

// ---------------------------------------------------------------------------
// Kernel 3: GCN aggregation + bias (fp32 edge weights)
// ---------------------------------------------------------------------------
__global__ void __launch_bounds__(256) gcn_agg(
    const float* __restrict__ xl, const int* __restrict__ ei,
    const float* __restrict__ ew, const float* __restrict__ gcn_b,
    float* __restrict__ Tpre){
  const int b = blockIdx.x, tid = threadIdx.x;
  __shared__ float sxl[15*256];
  __shared__ float s_deg[15], s_dinv[15], s_norm[71];
  __shared__ int   s_cnt[15], s_start[16], s_fill[15], s_srcl[71];
  if (tid < 15){ s_deg[tid] = 0.f; s_cnt[tid] = 0; s_fill[tid] = 0; }
  #pragma unroll
  for (int n = 0; n < 15; ++n)
    sxl[n*256 + tid] = xl[(size_t)(b*15 + n)*256 + tid];
  __syncthreads();
  int se = 0, de = 0; float we = 0.f;
  if (tid < 71){
    if (tid < 56){ se = ei[tid]; de = ei[56 + tid]; we = ew[tid]; }
    else         { se = tid - 56; de = tid - 56; we = 1.0f; }
    atomicAdd(&s_deg[de], we);
    atomicAdd(&s_cnt[de], 1);
  }
  __syncthreads();
  if (tid < 15) s_dinv[tid] = s_deg[tid] > 0.f ? rsqrtf(s_deg[tid]) : 0.f;
  if (tid == 0){
    int a = 0;
    for (int n = 0; n < 15; ++n){ s_start[n] = a; a += s_cnt[n]; }
    s_start[15] = a;
  }
  __syncthreads();
  if (tid < 71){
    float nrm = s_dinv[se]*we*s_dinv[de];
    int pos = s_start[de] + atomicAdd(&s_fill[de], 1);
    s_srcl[pos] = se; s_norm[pos] = nrm;
  }
  __syncthreads();
  const float gb = gcn_b[tid];
  for (int n = 0; n < 15; ++n){
    float acc = gb;
    const int e0 = s_start[n], e1 = s_start[n+1];
    for (int idx = e0; idx < e1; ++idx)
      acc += s_norm[idx]*sxl[s_srcl[idx]*256 + tid];
    Tpre[(size_t)(b*15 + n)*256 + tid] = acc;
  }
}

// ---------------------------------------------------------------------------
// Kernel 4: GraphNorm batch stats per (node, channel)
// ---------------------------------------------------------------------------
__global__ void __launch_bounds__(256) gn_stats(
    const float* __restrict__ Tpre, const float* __restrict__ gn_ms,
    const float* __restrict__ gn_w, float* __restrict__ moff, float* __restrict__ scal){
  const int n = blockIdx.x, c = threadIdx.x;
  float s = 0.f, s2 = 0.f;
  for (int b = 0; b < 128; ++b){
    float v = Tpre[(size_t)(b*15 + n)*256 + c];
    s += v; s2 += v*v;
  }
  const float mean = s*(1.f/128.f);
  const float mo = mean*gn_ms[c];
  float var = s2*(1.f/128.f) - 2.f*mo*mean + mo*mo;
  var = fmaxf(var, 0.f);
  moff[n*256 + c] = mo;
  scal[n*256 + c] = gn_w[c]*rsqrtf(var + 1e-5f);
}

// ---------------------------------------------------------------------------
// Kernel 5: normalize + lin1-add + ELU + node-mean pool + class head (fp32 out)
// ---------------------------------------------------------------------------
__global__ void __launch_bounds__(256) finalize_k(
    const float* __restrict__ Tpre, const float* __restrict__ l1,
    const float* __restrict__ moff, const float* __restrict__ scal,
    const float* __restrict__ gn_b, const float* __restrict__ lin1_b,
    const float* __restrict__ out_w, const float* __restrict__ out_b,
    float* __restrict__ dout){
  const int b = blockIdx.x, tid = threadIdx.x;
  __shared__ float spool[256], spart[256];
  const float gnb = gn_b[tid], lb = lin1_b[tid];
  float acc = 0.f;
  #pragma unroll
  for (int n = 0; n < 15; ++n){
    float t = (Tpre[(size_t)(b*15 + n)*256 + tid] - moff[n*256 + tid])*scal[n*256 + tid]
              + gnb + l1[(size_t)(b*15 + n)*256 + tid] + lb;
    t = t > 0.f ? t : (__expf(t) - 1.f);   // ELU(alpha=1)
    acc += t;
  }
  const float pool = acc*(1.f/15.f);
  dout[b*256 + tid] = pool;
  spool[tid] = pool;
  __syncthreads();
  const int j = tid >> 4, q = tid & 15;
  float s = 0.f;
  for (int i = 0; i < 16; ++i){
    int cc = q + i*16;
    s += spool[cc]*out_w[j*256 + cc];
  }
  spart[tid] = s;
  __syncthreads();
  if (tid < 16){
    float tot = out_b[tid];
    #pragma unroll
    for (int i = 0; i < 16; ++i) tot += spart[tid*16 + i];
    dout[32768 + b*16 + tid] = tot;
  }
}

// ---------------------------------------------------------------------------
extern "C" void kernel_launch(void* const* d_in, const int* in_sizes, int n_in,
                              void* d_out, int out_size, void* d_ws, size_t ws_size,
                              hipStream_t stream){
  (void)in_sizes; (void)n_in; (void)out_size; (void)ws_size;
  const float* X    = (const float*)d_in[0];
  const int*   ei   = (const int*)d_in[1];
  const float* ew   = (const float*)d_in[2];
  const float* w1   = (const float*)d_in[3];
  const float* b1   = (const float*)d_in[4];
  const float* w2   = (const float*)d_in[5];
  const float* b2   = (const float*)d_in[6];
  const float* w3   = (const float*)d_in[7];
  const float* b3   = (const float*)d_in[8];
  const float* gw   = (const float*)d_in[9];
  const float* gb   = (const float*)d_in[10];
  const float* lw   = (const float*)d_in[11];
  const float* lb   = (const float*)d_in[12];
  const float* gnw  = (const float*)d_in[13];
  const float* gnb  = (const float*)d_in[14];
  const float* gnms = (const float*)d_in[15];
  const float* ow   = (const float*)d_in[16];
  const float* ob   = (const float*)d_in[17];

  char* ws = (char*)d_ws;
  u16*   h3p  = (u16*)(ws + 0);              //  7,372,800 B
  u16*   gwp  = (u16*)(ws + 7372800);        //    983,040 B
  u16*   Xb   = (u16*)(ws + 8355840);        //  7,372,800 B
  u16*   lwb  = (u16*)(ws + 15728640);       //    983,040 B
  float* xl   = (float*)(ws + 16711680);     //  1,966,080 B
  float* l1   = (float*)(ws + 18677760);     //  1,966,080 B (end 20,643,840)
  float* Tpre = (float*)(ws + 0);            // reuse h3p (dead after gemm)
  float* moff = (float*)(ws + 7372800);      // reuse gwp (dead after gemm)
  float* scal = (float*)(ws + 7388160);

  cvt_bf16  <<<dim3(1800),       dim3(256), 0, stream>>>(X,  Xb,  128*15*1920);
  cvt_bf16  <<<dim3(480),        dim3(256), 0, stream>>>(lw, lwb, 256*1920);
  pad_gcnw  <<<dim3(256),        dim3(256), 0, stream>>>(gw, gwp);
  fused_conv<<<dim3(32, 16, 15), dim3(256), 0, stream>>>(X, w1, b1, w2, b2, w3, b3, h3p);
  gemm_nt   <<<dim3(30, 4, 2),   dim3(256), 0, stream>>>(Xb, lwb, l1, h3p, gwp, xl);
  gcn_agg   <<<dim3(128),        dim3(256), 0, stream>>>(xl, ei, ew, gb, Tpre);
  gn_stats  <<<dim3(15),         dim3(256), 0, stream>>>(Tpre, gnms, gnw, moff, scal);
  finalize_k<<<dim3(128),        dim3(256), 0, stream>>>(Tpre, l1, moff, scal,
                                                         gnb, lb, ow, ob, (float*)d_out);
}

// Round 6
// 235.526 us; speedup vs baseline: 1.2968x; 1.2968x over previous
//
#include <hip/hip_runtime.h>

typedef unsigned short u16;
typedef unsigned int   u32;

typedef short shortx8  __attribute__((ext_vector_type(8)));
typedef float floatx4  __attribute__((ext_vector_type(4)));
typedef u32   uintx4   __attribute__((ext_vector_type(4)));

typedef u32     u32a     __attribute__((may_alias));
typedef uintx4  uintx4a  __attribute__((may_alias));
typedef shortx8 shortx8a __attribute__((may_alias));

// accurate round-to-nearest-even (staging/weights)
__device__ __forceinline__ u16 f2bf(float f){
  union { float f; u32 i; } v; v.f = f;
  return (u16)((v.i + 0x7fffu + ((v.i >> 16) & 1u)) >> 16);
}
// fast round-half-up (hot path; max 0.5 ulp)
__device__ __forceinline__ u16 f2bf_fast(float f){
  union { float f; u32 i; } v; v.f = f;
  return (u16)((v.i + 0x8000u) >> 16);
}
__device__ __forceinline__ u32 pack_bf16_fast(float lo, float hi){
  union { float f; u32 i; } a, b; a.f = lo; b.f = hi;
  return ((a.i + 0x8000u) >> 16) | ((b.i + 0x8000u) & 0xFFFF0000u);
}

// ---------------------------------------------------------------------------
// Kernel 0: prep — lin1_w fp32->bf16 (blocks 0..479) + gcn_w pad+cvt (480..735)
// ---------------------------------------------------------------------------
__global__ void __launch_bounds__(256) prep(const float* __restrict__ lw,
                                            u16* __restrict__ lwb,
                                            const float* __restrict__ gw,
                                            u16* __restrict__ gwp){
  const int b = blockIdx.x, tid = threadIdx.x;
  if (b < 480){
    const int base = b*1024 + tid;
    #pragma unroll
    for (int u = 0; u < 4; ++u) lwb[base + 256*u] = f2bf(lw[base + 256*u]);
  } else {
    const int row = b - 480;
    for (int col = tid; col < 1920; col += 256)
      gwp[row*1920 + col] = (col < 1908) ? f2bf(gw[row*1908 + col]) : (u16)0;
  }
}

// ---------------------------------------------------------------------------
// Kernel 1: fused conv1 (VALU) -> conv2 -> conv3 (MFMA 16x16x32 bf16).
// Per-wave LDS slots, but cross-lane LDS handoffs (conv1->conv2->conv3) are
// inter-thread communication: they REQUIRE __syncthreads() as a compiler
// memory fence (round-5 lesson: "same-wave DS in-order" is a HW property,
// not a memory-model one — without the barrier the compiler may reorder
// per-lane-disjoint LDS accesses and a subset of fragments read stale data).
// Also emits Xb (bf16 copy of X) during staging.
// grid (32 t-tiles, 16 b-groups, 15 nodes), block 256 (4 waves).
// ---------------------------------------------------------------------------
__global__ void __launch_bounds__(256) fused_conv(
    const float* __restrict__ X,
    const float* __restrict__ w1, const float* __restrict__ b1,
    const float* __restrict__ w2, const float* __restrict__ b2,
    const float* __restrict__ w3, const float* __restrict__ b3,
    u16* __restrict__ h3p, u16* __restrict__ Xb){
  const int tid  = threadIdx.x;
  const int node = blockIdx.z;
  const int p    = blockIdx.x * 60;
  const int b0   = blockIdx.y * 8;

  __shared__ __attribute__((aligned(16))) u16 sH1[4*1632];  // per-wave [68][24]
  __shared__ __attribute__((aligned(16))) u16 sH2[4*2720];  // per-wave [68][40]
  __shared__ __attribute__((aligned(16))) u16 sW2f[3072];   // frag order [(o*3+pi)][quad][m][j]
  __shared__ __attribute__((aligned(16))) u16 sW3f[160];    // [tap][ic32]
  __shared__ float sX[8*76];
  __shared__ float sW1[80], sB1[16], sB2[32];

  // ---- staging ----
  {
    const int bls = tid >> 5, i0 = tid & 31;
    const float* xrow = X  + (size_t)((b0 + bls)*15 + node)*1920;
    u16*        xbrow = Xb + (size_t)((b0 + bls)*15 + node)*1920;
    #pragma unroll
    for (int u = 0; u < 3; ++u){
      int i = i0 + 32*u;
      if (i < 76){
        int g = p + i;
        float xv = (i < 72 && g < 1920) ? xrow[g] : 0.f;
        sX[bls*76 + i] = xv;
        if (i < 60) xbrow[g] = f2bf_fast(xv);   // i<60 => g<1920 always
      }
    }
    // w2 into A-fragment order: idx = ((o*3+pi)*4+quad)*128 + m*8 + j
    #pragma unroll
    for (int u = 0; u < 12; ++u){
      int d = tid + 256*u;
      int j = d & 7, mm = (d >> 3) & 15, qd = (d >> 7) & 3, t6 = d >> 9; // 0..5
      int o = (t6 >= 3) ? 1 : 0, pi = t6 - 3*o;
      int tap = 2*pi + (qd >> 1), icc = (qd & 1)*8 + j, oc = o*16 + mm;
      sW2f[d] = (tap < 5) ? f2bf(w2[node*2560 + (oc*16 + icc)*5 + tap]) : (u16)0;
    }
    if (tid < 160){
      int icc = tid / 5, tp = tid - 5*icc;
      sW3f[tp*32 + icc] = f2bf(w3[node*160 + tid]);
    }
    if (tid < 80) sW1[tid] = w1[node*80 + tid];
    if (tid < 16) sB1[tid] = b1[node*16 + tid];
    if (tid < 32) sB2[tid] = b2[node*32 + tid];
  }
  __syncthreads();

  const int w = tid >> 6, lane = tid & 63;
  const int m = lane & 15, quad = lane >> 4;
  const int icb = (quad & 1)*8;   // ic base within K
  const int tpo = quad >> 1;      // tap offset within pair

  // conv2 A-frags: 6 vector LDS loads (pre-formatted)
  shortx8 a2[2][3];
  #pragma unroll
  for (int o = 0; o < 2; ++o)
    #pragma unroll
    for (int pi = 0; pi < 3; ++pi)
      a2[o][pi] = *(const shortx8a*)&sW2f[((o*3 + pi)*4 + quad)*128 + m*8];

  // conv3 A-frags: only row m=0 nonzero
  shortx8 a3[5];
  {
    const shortx8 zv = {0,0,0,0,0,0,0,0};
    #pragma unroll
    for (int tp = 0; tp < 5; ++tp){
      shortx8 t = *(const shortx8a*)&sW3f[tp*32 + quad*8];
      a3[tp] = (m == 0) ? t : zv;
    }
  }
  float biasr2[2][4];
  #pragma unroll
  for (int o = 0; o < 2; ++o)
    #pragma unroll
    for (int r = 0; r < 4; ++r)
      biasr2[o][r] = sB2[o*16 + quad*4 + r];
  const float b3v = b3[node];

  u16* h1w = sH1 + w*1632;
  u16* h2w = sH2 + w*2720;
  // zero sH2 tail rows 64..67 once (conv2 writes only rows 0..63);
  // ordered before conv3's reads by the barriers inside the bb loop.
  for (int i = lane; i < 160; i += 64) h2w[2560 + i] = 0;

  // conv1 per-lane role: 8 ic-pairs x 8 t-chunks of 9
  const int c1ic = (lane & 7)*2, c1t0 = (lane >> 3)*9;
  float wa[5], wb[5];
  #pragma unroll
  for (int k = 0; k < 5; ++k){ wa[k] = sW1[c1ic*5 + k]; wb[k] = sW1[c1ic*5 + 5 + k]; }
  const float ba = sB1[c1ic], bbv = sB1[c1ic + 1];

  for (int bb = 0; bb < 2; ++bb){
    const int bl = w + bb*4;

    // ---- conv1 (VALU) for this wave's batch ----
    {
      const float* xr = sX + bl*76;
      float x0 = xr[c1t0], x1 = xr[c1t0+1], x2 = xr[c1t0+2], x3 = xr[c1t0+3];
      #pragma unroll
      for (int i = 0; i < 9; ++i){
        const int t = c1t0 + i;
        float x4 = xr[t + 4];
        float va = ba  + wa[0]*x0 + wa[1]*x1 + wa[2]*x2 + wa[3]*x3 + wa[4]*x4;
        float vb = bbv + wb[0]*x0 + wb[1]*x1 + wb[2]*x2 + wb[3]*x3 + wb[4]*x4;
        va = va > 0.f ? va : 0.01f*va;
        vb = vb > 0.f ? vb : 0.01f*vb;
        if (t < 68) *(u32a*)(h1w + t*24 + c1ic) = pack_bf16_fast(va, vb);
        x0 = x1; x1 = x2; x2 = x3; x3 = x4;
      }
    }
    __syncthreads();   // conv1 writes -> conv2 reads (cross-lane LDS handoff)

    // ---- conv2: q-outer (B-frags shared by both oc-halves) ----
    #pragma unroll
    for (int q = 0; q < 4; ++q){
      const int trow = q*16 + m;
      shortx8 bf0 = *(const shortx8a*)(h1w + (trow     + tpo)*24 + icb);
      shortx8 bf1 = *(const shortx8a*)(h1w + (trow + 2 + tpo)*24 + icb);
      shortx8 bf2 = *(const shortx8a*)(h1w + (trow + 4      )*24 + icb);
      floatx4 ac0 = {0.f,0.f,0.f,0.f}, ac1 = {0.f,0.f,0.f,0.f};
      ac0 = __builtin_amdgcn_mfma_f32_16x16x32_bf16(a2[0][0], bf0, ac0, 0, 0, 0);
      ac1 = __builtin_amdgcn_mfma_f32_16x16x32_bf16(a2[1][0], bf0, ac1, 0, 0, 0);
      ac0 = __builtin_amdgcn_mfma_f32_16x16x32_bf16(a2[0][1], bf1, ac0, 0, 0, 0);
      ac1 = __builtin_amdgcn_mfma_f32_16x16x32_bf16(a2[1][1], bf1, ac1, 0, 0, 0);
      ac0 = __builtin_amdgcn_mfma_f32_16x16x32_bf16(a2[0][2], bf2, ac0, 0, 0, 0);
      ac1 = __builtin_amdgcn_mfma_f32_16x16x32_bf16(a2[1][2], bf2, ac1, 0, 0, 0);
      #pragma unroll
      for (int o = 0; o < 2; ++o){
        const floatx4& ac = o ? ac1 : ac0;
        float v0 = ac[0] + biasr2[o][0];
        float v1 = ac[1] + biasr2[o][1];
        float v2 = ac[2] + biasr2[o][2];
        float v3 = ac[3] + biasr2[o][3];
        v0 = v0 > 0.f ? v0 : 0.01f*v0;
        v1 = v1 > 0.f ? v1 : 0.01f*v1;
        v2 = v2 > 0.f ? v2 : 0.01f*v2;
        v3 = v3 > 0.f ? v3 : 0.01f*v3;
        u16* dst = h2w + trow*40 + o*16 + quad*4;
        *(u32a*)(dst)     = pack_bf16_fast(v0, v1);
        *(u32a*)(dst + 2) = pack_bf16_fast(v2, v3);
      }
    }
    __syncthreads();   // conv2 writes -> conv3 reads (cross-lane LDS handoff)

    // ---- conv3: 4 t-tiles, 5 tap MFMAs; result in D row 0 ----
    const int rg = (b0 + bl)*15 + node;
    #pragma unroll
    for (int nt = 0; nt < 4; ++nt){
      floatx4 acc3 = {0.f,0.f,0.f,0.f};
      if (lane < 16) acc3[0] = b3v;
      #pragma unroll
      for (int tp = 0; tp < 5; ++tp){
        shortx8 bfr = *(const shortx8a*)(h2w + (nt*16 + m + tp)*40 + quad*8);
        acc3 = __builtin_amdgcn_mfma_f32_16x16x32_bf16(a3[tp], bfr, acc3, 0, 0, 0);
      }
      const int tl = nt*16 + lane;
      if (lane < 16 && tl < 60){
        const int t3 = p + tl;
        float v = acc3[0];
        v = v > 0.f ? v : 0.01f*v;
        h3p[(size_t)rg*1920 + t3] = (t3 < 1908) ? f2bf_fast(v) : (u16)0;
      }
    }
  }
}

// ---------------------------------------------------------------------------
// Kernel 2: NT GEMM  O[1920][256] += A[1920][1920] * B[256][1920]^T
// grid (30,4,4): z>>1 = job (0: Xb*lwb->l1, 1: h3p*gwp->xl), z&1 = K-half.
// Outputs pre-zeroed; epilogue uses fp32 atomicAdd.
// ---------------------------------------------------------------------------
__global__ void __launch_bounds__(256) gemm_nt(
    const u16* __restrict__ A0, const u16* __restrict__ B0, float* __restrict__ O0,
    const u16* __restrict__ A1, const u16* __restrict__ B1, float* __restrict__ O1){
  const int job = blockIdx.z >> 1, kh = blockIdx.z & 1;
  const u16* A; const u16* Bm; float* O;
  if (job == 0){ A = A0; Bm = B0; O = O0; } else { A = A1; Bm = B1; O = O1; }
  __shared__ __attribute__((aligned(16))) u16 sA[64*40];
  __shared__ __attribute__((aligned(16))) u16 sB[64*40];
  const int tid = threadIdx.x;
  const int m0 = blockIdx.x*64, n0 = blockIdx.y*64;
  const int row = tid >> 2, kc = tid & 3;
  const int w = tid >> 6, lane = tid & 63;
  const int mo = (w & 1)*32, no = (w >> 1)*32;
  floatx4 acc[2][2];
  #pragma unroll
  for (int i = 0; i < 2; ++i)
    #pragma unroll
    for (int j = 0; j < 2; ++j)
      #pragma unroll
      for (int r = 0; r < 4; ++r) acc[i][j][r] = 0.f;

  const u16* ap = A  + (size_t)(m0 + row)*1920 + kh*960 + kc*8;
  const u16* bp = Bm + (size_t)(n0 + row)*1920 + kh*960 + kc*8;
  for (int kt = 0; kt < 30; ++kt){
    uintx4 va = *(const uintx4a*)ap;
    uintx4 vb = *(const uintx4a*)bp;
    ap += 32; bp += 32;
    *(uintx4a*)&sA[row*40 + kc*8] = va;
    *(uintx4a*)&sB[row*40 + kc*8] = vb;
    __syncthreads();
    const shortx8 af0 = *(const shortx8a*)&sA[(mo      + (lane & 15))*40 + (lane >> 4)*8];
    const shortx8 af1 = *(const shortx8a*)&sA[(mo + 16 + (lane & 15))*40 + (lane >> 4)*8];
    const shortx8 bf0 = *(const shortx8a*)&sB[(no      + (lane & 15))*40 + (lane >> 4)*8];
    const shortx8 bf1 = *(const shortx8a*)&sB[(no + 16 + (lane & 15))*40 + (lane >> 4)*8];
    acc[0][0] = __builtin_amdgcn_mfma_f32_16x16x32_bf16(af0, bf0, acc[0][0], 0, 0, 0);
    acc[0][1] = __builtin_amdgcn_mfma_f32_16x16x32_bf16(af0, bf1, acc[0][1], 0, 0, 0);
    acc[1][0] = __builtin_amdgcn_mfma_f32_16x16x32_bf16(af1, bf0, acc[1][0], 0, 0, 0);
    acc[1][1] = __builtin_amdgcn_mfma_f32_16x16x32_bf16(af1, bf1, acc[1][1], 0, 0, 0);
    __syncthreads();
  }
  #pragma unroll
  for (int mi = 0; mi < 2; ++mi)
    #pragma unroll
    for (int ni = 0; ni < 2; ++ni)
      #pragma unroll
      for (int r = 0; r < 4; ++r){
        int rr = m0 + mo + mi*16 + (lane >> 4)*4 + r;
        int cc = n0 + no + ni*16 + (lane & 15);
        atomicAdd(&O[(size_t)rr*256 + cc], acc[mi][ni][r]);
      }
}

// ---------------------------------------------------------------------------
// Kernel 3: GCN aggregation + bias
// ---------------------------------------------------------------------------
__global__ void __launch_bounds__(256) gcn_agg(
    const float* __restrict__ xl, const int* __restrict__ ei,
    const float* __restrict__ ew, const float* __restrict__ gcn_b,
    float* __restrict__ Tpre){
  const int b = blockIdx.x, tid = threadIdx.x;
  __shared__ float sxl[15*256];
  __shared__ float s_deg[15], s_dinv[15], s_norm[71];
  __shared__ int   s_cnt[15], s_start[16], s_fill[15], s_srcl[71];
  if (tid < 15){ s_deg[tid] = 0.f; s_cnt[tid] = 0; s_fill[tid] = 0; }
  #pragma unroll
  for (int n = 0; n < 15; ++n)
    sxl[n*256 + tid] = xl[(size_t)(b*15 + n)*256 + tid];
  __syncthreads();
  int se = 0, de = 0; float we = 0.f;
  if (tid < 71){
    if (tid < 56){ se = ei[tid]; de = ei[56 + tid]; we = ew[tid]; }
    else         { se = tid - 56; de = tid - 56; we = 1.0f; }
    atomicAdd(&s_deg[de], we);
    atomicAdd(&s_cnt[de], 1);
  }
  __syncthreads();
  if (tid < 15) s_dinv[tid] = s_deg[tid] > 0.f ? rsqrtf(s_deg[tid]) : 0.f;
  if (tid == 0){
    int a = 0;
    for (int n = 0; n < 15; ++n){ s_start[n] = a; a += s_cnt[n]; }
    s_start[15] = a;
  }
  __syncthreads();
  if (tid < 71){
    float nrm = s_dinv[se]*we*s_dinv[de];
    int pos = s_start[de] + atomicAdd(&s_fill[de], 1);
    s_srcl[pos] = se; s_norm[pos] = nrm;
  }
  __syncthreads();
  const float gb = gcn_b[tid];
  for (int n = 0; n < 15; ++n){
    float acc = gb;
    const int e0 = s_start[n], e1 = s_start[n+1];
    for (int idx = e0; idx < e1; ++idx)
      acc += s_norm[idx]*sxl[s_srcl[idx]*256 + tid];
    Tpre[(size_t)(b*15 + n)*256 + tid] = acc;
  }
}

// ---------------------------------------------------------------------------
// Kernel 4: GraphNorm batch stats per (node, channel)
// ---------------------------------------------------------------------------
__global__ void __launch_bounds__(256) gn_stats(
    const float* __restrict__ Tpre, const float* __restrict__ gn_ms,
    const float* __restrict__ gn_w, float* __restrict__ moff, float* __restrict__ scal){
  const int n = blockIdx.x, c = threadIdx.x;
  float s = 0.f, s2 = 0.f;
  for (int b = 0; b < 128; ++b){
    float v = Tpre[(size_t)(b*15 + n)*256 + c];
    s += v; s2 += v*v;
  }
  const float mean = s*(1.f/128.f);
  const float mo = mean*gn_ms[c];
  float var = s2*(1.f/128.f) - 2.f*mo*mean + mo*mo;
  var = fmaxf(var, 0.f);
  moff[n*256 + c] = mo;
  scal[n*256 + c] = gn_w[c]*rsqrtf(var + 1e-5f);
}

// ---------------------------------------------------------------------------
// Kernel 5: normalize + lin1-add + ELU + node-mean pool + class head
// ---------------------------------------------------------------------------
__global__ void __launch_bounds__(256) finalize_k(
    const float* __restrict__ Tpre, const float* __restrict__ l1,
    const float* __restrict__ moff, const float* __restrict__ scal,
    const float* __restrict__ gn_b, const float* __restrict__ lin1_b,
    const float* __restrict__ out_w, const float* __restrict__ out_b,
    float* __restrict__ dout){
  const int b = blockIdx.x, tid = threadIdx.x;
  __shared__ float spool[256], spart[256];
  const float gnb = gn_b[tid], lb = lin1_b[tid];
  float acc = 0.f;
  #pragma unroll
  for (int n = 0; n < 15; ++n){
    float t = (Tpre[(size_t)(b*15 + n)*256 + tid] - moff[n*256 + tid])*scal[n*256 + tid]
              + gnb + l1[(size_t)(b*15 + n)*256 + tid] + lb;
    t = t > 0.f ? t : (__expf(t) - 1.f);   // ELU(alpha=1)
    acc += t;
  }
  const float pool = acc*(1.f/15.f);
  dout[b*256 + tid] = pool;
  spool[tid] = pool;
  __syncthreads();
  const int j = tid >> 4, q = tid & 15;
  float s = 0.f;
  for (int i = 0; i < 16; ++i){
    int cc = q + i*16;
    s += spool[cc]*out_w[j*256 + cc];
  }
  spart[tid] = s;
  __syncthreads();
  if (tid < 16){
    float tot = out_b[tid];
    #pragma unroll
    for (int i = 0; i < 16; ++i) tot += spart[tid*16 + i];
    dout[32768 + b*16 + tid] = tot;
  }
}

// ---------------------------------------------------------------------------
extern "C" void kernel_launch(void* const* d_in, const int* in_sizes, int n_in,
                              void* d_out, int out_size, void* d_ws, size_t ws_size,
                              hipStream_t stream){
  (void)in_sizes; (void)n_in; (void)out_size; (void)ws_size;
  const float* X    = (const float*)d_in[0];
  const int*   ei   = (const int*)d_in[1];
  const float* ew   = (const float*)d_in[2];
  const float* w1   = (const float*)d_in[3];
  const float* b1   = (const float*)d_in[4];
  const float* w2   = (const float*)d_in[5];
  const float* b2   = (const float*)d_in[6];
  const float* w3   = (const float*)d_in[7];
  const float* b3   = (const float*)d_in[8];
  const float* gw   = (const float*)d_in[9];
  const float* gb   = (const float*)d_in[10];
  const float* lw   = (const float*)d_in[11];
  const float* lb   = (const float*)d_in[12];
  const float* gnw  = (const float*)d_in[13];
  const float* gnb  = (const float*)d_in[14];
  const float* gnms = (const float*)d_in[15];
  const float* ow   = (const float*)d_in[16];
  const float* ob   = (const float*)d_in[17];

  char* ws = (char*)d_ws;
  u16*   h3p  = (u16*)(ws + 0);              //  7,372,800 B
  u16*   gwp  = (u16*)(ws + 7372800);        //    983,040 B
  u16*   Xb   = (u16*)(ws + 8355840);        //  7,372,800 B
  u16*   lwb  = (u16*)(ws + 15728640);       //    983,040 B
  float* xl   = (float*)(ws + 16711680);     //  1,966,080 B
  float* l1   = (float*)(ws + 18677760);     //  1,966,080 B (end 20,643,840)
  float* Tpre = (float*)(ws + 0);            // reuse h3p (dead after gemm)
  float* moff = (float*)(ws + 7372800);      // reuse gwp (dead after gemm)
  float* scal = (float*)(ws + 7388160);

  hipMemsetAsync(ws + 16711680, 0, 3932160, stream);   // zero xl + l1 (adjacent)
  prep      <<<dim3(736),        dim3(256), 0, stream>>>(lw, lwb, gw, gwp);
  fused_conv<<<dim3(32, 16, 15), dim3(256), 0, stream>>>(X, w1, b1, w2, b2, w3, b3,
                                                         h3p, Xb);
  gemm_nt   <<<dim3(30, 4, 4),   dim3(256), 0, stream>>>(Xb, lwb, l1, h3p, gwp, xl);
  gcn_agg   <<<dim3(128),        dim3(256), 0, stream>>>(xl, ei, ew, gb, Tpre);
  gn_stats  <<<dim3(15),         dim3(256), 0, stream>>>(Tpre, gnms, gnw, moff, scal);
  finalize_k<<<dim3(128),        dim3(256), 0, stream>>>(Tpre, l1, moff, scal,
                                                         gnb, lb, ow, ob, (float*)d_out);
}

// Round 7
// 219.386 us; speedup vs baseline: 1.3922x; 1.0736x over previous
//
#include <hip/hip_runtime.h>

typedef unsigned short u16;
typedef unsigned int   u32;

typedef short shortx8  __attribute__((ext_vector_type(8)));
typedef float floatx4  __attribute__((ext_vector_type(4)));
typedef u32   uintx4   __attribute__((ext_vector_type(4)));

typedef u32     u32a     __attribute__((may_alias));
typedef uintx4  uintx4a  __attribute__((may_alias));
typedef shortx8 shortx8a __attribute__((may_alias));

__device__ __forceinline__ float bf2f(u16 u){
  union { u32 i; float f; } v; v.i = ((u32)u) << 16; return v.f;
}
// accurate round-to-nearest-even (weights)
__device__ __forceinline__ u16 f2bf(float f){
  union { float f; u32 i; } v; v.f = f;
  return (u16)((v.i + 0x7fffu + ((v.i >> 16) & 1u)) >> 16);
}
// fast round-half-up (hot path; max 0.5 ulp)
__device__ __forceinline__ u16 f2bf_fast(float f){
  union { float f; u32 i; } v; v.f = f;
  return (u16)((v.i + 0x8000u) >> 16);
}
// pack two bf16 (round-half-up) via v_perm_b32: 3 VALU ops
__device__ __forceinline__ u32 pack2(float lo, float hi){
  union { float f; u32 i; } a, b; a.f = lo; b.f = hi;
  return __builtin_amdgcn_perm(b.i + 0x8000u, a.i + 0x8000u, 0x07060302u);
}
__device__ __forceinline__ float lrelu(float v){ return fmaxf(v, 0.01f*v); }

// ---------------------------------------------------------------------------
// Kernel 0: prep — lin1_w cvt (blocks 0..479) + gcn_w pad+cvt (480..735)
//           + zero xl/l1 accumulators (all blocks; replaces hipMemsetAsync)
// ---------------------------------------------------------------------------
__global__ void __launch_bounds__(256) prep(const float* __restrict__ lw,
                                            u16* __restrict__ lwb,
                                            const float* __restrict__ gw,
                                            u16* __restrict__ gwp,
                                            float* __restrict__ zbase){
  const int b = blockIdx.x, tid = threadIdx.x;
  if (b < 480){
    const int base = b*1024 + tid;
    #pragma unroll
    for (int u = 0; u < 4; ++u) lwb[base + 256*u] = f2bf(lw[base + 256*u]);
  } else {
    const int row = b - 480;
    for (int col = tid; col < 1920; col += 256)
      gwp[row*1920 + col] = (col < 1908) ? f2bf(gw[row*1908 + col]) : (u16)0;
  }
  const int gidx = b*256 + tid;
  #pragma unroll
  for (int u = 0; u < 6; ++u){
    int i = gidx + u*188416;
    if (i < 983040) zbase[i] = 0.f;
  }
}

// ---------------------------------------------------------------------------
// Kernel 1: fused conv1 (VALU) -> conv2 -> conv3 (MFMA 16x16x32 bf16).
// 512 threads = 8 waves; per-wave LDS slots; barriers at cross-lane LDS
// handoffs (compiler memory fence — round-5 lesson). ~79.2 KB LDS ->
// 2 blocks/CU = 16 waves/CU. Emits Xb (bf16 X) during staging.
// grid (32 t-tiles, 8 b-groups, 15 nodes).
// ---------------------------------------------------------------------------
__global__ void __launch_bounds__(512, 4) fused_conv(
    const float* __restrict__ X,
    const float* __restrict__ w1, const float* __restrict__ b1,
    const float* __restrict__ w2, const float* __restrict__ b2,
    const float* __restrict__ w3, const float* __restrict__ b3,
    u16* __restrict__ h3p, u16* __restrict__ Xb){
  const int tid  = threadIdx.x;
  const int node = blockIdx.z;
  const int p    = blockIdx.x * 60;
  const int b0   = blockIdx.y * 16;

  __shared__ __attribute__((aligned(16))) u16 sH1[8*1632];  // per-wave [68][24]
  __shared__ __attribute__((aligned(16))) u16 sH2[8*2720];  // per-wave [68][40]
  __shared__ __attribute__((aligned(16))) u16 sW2f[3072];   // frag order
  __shared__ __attribute__((aligned(16))) u16 sW3f[160];    // [tap][ic32]
  __shared__ u16 sXb[16*76];                                // bf16 X window
  __shared__ float sW1[80], sB1[16], sB2[32];

  // ---- staging ----
  {
    const int bls = tid >> 5, i0 = tid & 31;
    const float* xrow = X  + (size_t)((b0 + bls)*15 + node)*1920;
    u16*        xbrow = Xb + (size_t)((b0 + bls)*15 + node)*1920;
    #pragma unroll
    for (int u = 0; u < 3; ++u){
      int i = i0 + 32*u;
      if (i < 76){
        int g = p + i;
        float xv = (i < 72 && g < 1920) ? xrow[g] : 0.f;
        u16 xb = f2bf_fast(xv);
        sXb[bls*76 + i] = xb;
        if (i < 60) xbrow[g] = xb;   // i<60 => g<1920 always
      }
    }
    // w2 into A-fragment order: idx = ((o*3+pi)*4+quad)*128 + m*8 + j
    #pragma unroll
    for (int u = 0; u < 6; ++u){
      int d = tid + 512*u;
      int j = d & 7, mm = (d >> 3) & 15, qd = (d >> 7) & 3, t6 = d >> 9; // 0..5
      int o = (t6 >= 3) ? 1 : 0, pi = t6 - 3*o;
      int tap = 2*pi + (qd >> 1), icc = (qd & 1)*8 + j, oc = o*16 + mm;
      sW2f[d] = (tap < 5) ? f2bf(w2[node*2560 + (oc*16 + icc)*5 + tap]) : (u16)0;
    }
    if (tid < 160){
      int icc = tid / 5, tp = tid - 5*icc;
      sW3f[tp*32 + icc] = f2bf(w3[node*160 + tid]);
    }
    if (tid < 80) sW1[tid] = w1[node*80 + tid];
    if (tid < 16) sB1[tid] = b1[node*16 + tid];
    if (tid < 32) sB2[tid] = b2[node*32 + tid];
  }
  __syncthreads();

  const int w = tid >> 6, lane = tid & 63;
  const int m = lane & 15, quad = lane >> 4;
  const int icb = (quad & 1)*8;   // ic base within K
  const int tpo = quad >> 1;      // tap offset within pair

  // conv2 A-frags: 6 vector LDS loads (pre-formatted)
  shortx8 a2[2][3];
  #pragma unroll
  for (int o = 0; o < 2; ++o)
    #pragma unroll
    for (int pi = 0; pi < 3; ++pi)
      a2[o][pi] = *(const shortx8a*)&sW2f[((o*3 + pi)*4 + quad)*128 + m*8];

  // conv3 A-frags: only row m=0 nonzero
  shortx8 a3[5];
  {
    const shortx8 zv = {0,0,0,0,0,0,0,0};
    #pragma unroll
    for (int tp = 0; tp < 5; ++tp){
      shortx8 t = *(const shortx8a*)&sW3f[tp*32 + quad*8];
      a3[tp] = (m == 0) ? t : zv;
    }
  }
  float biasr2[2][4];
  #pragma unroll
  for (int o = 0; o < 2; ++o)
    #pragma unroll
    for (int r = 0; r < 4; ++r)
      biasr2[o][r] = sB2[o*16 + quad*4 + r];
  const float b3v = b3[node];

  u16* h1w = sH1 + w*1632;
  u16* h2w = sH2 + w*2720;
  // zero sH2 tail rows 64..67 once (conv2 writes only rows 0..63);
  // ordered before conv3's reads by the barriers inside the bb loop.
  for (int i = lane; i < 160; i += 64) h2w[2560 + i] = 0;

  // conv1 per-lane role: 8 ic-pairs x 8 t-chunks of 9
  const int c1ic = (lane & 7)*2, c1t0 = (lane >> 3)*9;
  float wa[5], wb[5];
  #pragma unroll
  for (int k = 0; k < 5; ++k){ wa[k] = sW1[c1ic*5 + k]; wb[k] = sW1[c1ic*5 + 5 + k]; }
  const float ba = sB1[c1ic], bbv = sB1[c1ic + 1];

  for (int bb = 0; bb < 2; ++bb){
    const int bl = w + bb*8;

    // ---- conv1 (VALU) for this wave's batch ----
    {
      const u16* xr = sXb + bl*76;
      float x0 = bf2f(xr[c1t0]),   x1 = bf2f(xr[c1t0+1]);
      float x2 = bf2f(xr[c1t0+2]), x3 = bf2f(xr[c1t0+3]);
      #pragma unroll
      for (int i = 0; i < 9; ++i){
        const int t = c1t0 + i;
        float x4 = bf2f(xr[t + 4]);
        float va = ba  + wa[0]*x0 + wa[1]*x1 + wa[2]*x2 + wa[3]*x3 + wa[4]*x4;
        float vb = bbv + wb[0]*x0 + wb[1]*x1 + wb[2]*x2 + wb[3]*x3 + wb[4]*x4;
        va = lrelu(va); vb = lrelu(vb);
        if (t < 68) *(u32a*)(h1w + t*24 + c1ic) = pack2(va, vb);
        x0 = x1; x1 = x2; x2 = x3; x3 = x4;
      }
    }
    __syncthreads();   // conv1 writes -> conv2 reads (cross-lane LDS handoff)

    // ---- conv2: q-outer (B-frags shared by both oc-halves) ----
    #pragma unroll
    for (int q = 0; q < 4; ++q){
      const int trow = q*16 + m;
      shortx8 bf0 = *(const shortx8a*)(h1w + (trow     + tpo)*24 + icb);
      shortx8 bf1 = *(const shortx8a*)(h1w + (trow + 2 + tpo)*24 + icb);
      shortx8 bf2 = *(const shortx8a*)(h1w + (trow + 4      )*24 + icb);
      floatx4 ac0 = {0.f,0.f,0.f,0.f}, ac1 = {0.f,0.f,0.f,0.f};
      ac0 = __builtin_amdgcn_mfma_f32_16x16x32_bf16(a2[0][0], bf0, ac0, 0, 0, 0);
      ac1 = __builtin_amdgcn_mfma_f32_16x16x32_bf16(a2[1][0], bf0, ac1, 0, 0, 0);
      ac0 = __builtin_amdgcn_mfma_f32_16x16x32_bf16(a2[0][1], bf1, ac0, 0, 0, 0);
      ac1 = __builtin_amdgcn_mfma_f32_16x16x32_bf16(a2[1][1], bf1, ac1, 0, 0, 0);
      ac0 = __builtin_amdgcn_mfma_f32_16x16x32_bf16(a2[0][2], bf2, ac0, 0, 0, 0);
      ac1 = __builtin_amdgcn_mfma_f32_16x16x32_bf16(a2[1][2], bf2, ac1, 0, 0, 0);
      #pragma unroll
      for (int o = 0; o < 2; ++o){
        const floatx4& ac = o ? ac1 : ac0;
        float v0 = lrelu(ac[0] + biasr2[o][0]);
        float v1 = lrelu(ac[1] + biasr2[o][1]);
        float v2 = lrelu(ac[2] + biasr2[o][2]);
        float v3 = lrelu(ac[3] + biasr2[o][3]);
        u16* dst = h2w + trow*40 + o*16 + quad*4;
        *(u32a*)(dst)     = pack2(v0, v1);
        *(u32a*)(dst + 2) = pack2(v2, v3);
      }
    }
    __syncthreads();   // conv2 writes -> conv3 reads (cross-lane LDS handoff)

    // ---- conv3: 4 t-tiles, 5 tap MFMAs; result in D row 0 ----
    const int rg = (b0 + bl)*15 + node;
    #pragma unroll
    for (int nt = 0; nt < 4; ++nt){
      floatx4 acc3 = {0.f,0.f,0.f,0.f};
      if (lane < 16) acc3[0] = b3v;
      #pragma unroll
      for (int tp = 0; tp < 5; ++tp){
        shortx8 bfr = *(const shortx8a*)(h2w + (nt*16 + m + tp)*40 + quad*8);
        acc3 = __builtin_amdgcn_mfma_f32_16x16x32_bf16(a3[tp], bfr, acc3, 0, 0, 0);
      }
      const int tl = nt*16 + lane;
      if (lane < 16 && tl < 60){
        const int t3 = p + tl;
        float v = lrelu(acc3[0]);
        h3p[(size_t)rg*1920 + t3] = (t3 < 1908) ? f2bf_fast(v) : (u16)0;
      }
    }
  }
}

// ---------------------------------------------------------------------------
// Kernel 2: NT GEMM  O[1920][256] += A[1920][1920] * B[256][1920]^T
// grid (30,4,4): z>>1 = job (0: Xb*lwb->l1, 1: h3p*gwp->xl), z&1 = K-half.
// K-step 64 (halved barrier count); LDS stride 88 u16 (2-way banks only).
// Outputs pre-zeroed by prep; epilogue uses fp32 atomicAdd.
// ---------------------------------------------------------------------------
__global__ void __launch_bounds__(256) gemm_nt(
    const u16* __restrict__ A0, const u16* __restrict__ B0, float* __restrict__ O0,
    const u16* __restrict__ A1, const u16* __restrict__ B1, float* __restrict__ O1){
  const int job = blockIdx.z >> 1, kh = blockIdx.z & 1;
  const u16* A; const u16* Bm; float* O;
  if (job == 0){ A = A0; Bm = B0; O = O0; } else { A = A1; Bm = B1; O = O1; }
  __shared__ __attribute__((aligned(16))) u16 sA[64*88];
  __shared__ __attribute__((aligned(16))) u16 sB[64*88];
  const int tid = threadIdx.x;
  const int m0 = blockIdx.x*64, n0 = blockIdx.y*64;
  const int row = tid >> 2, kc = tid & 3;
  const int w = tid >> 6, lane = tid & 63;
  const int m = lane & 15, quad = lane >> 4;
  const int mo = (w & 1)*32, no = (w >> 1)*32;
  floatx4 acc[2][2];
  #pragma unroll
  for (int i = 0; i < 2; ++i)
    #pragma unroll
    for (int j = 0; j < 2; ++j)
      #pragma unroll
      for (int r = 0; r < 4; ++r) acc[i][j][r] = 0.f;

  const u16* ap = A  + (size_t)(m0 + row)*1920 + kh*960 + kc*8;
  const u16* bp = Bm + (size_t)(n0 + row)*1920 + kh*960 + kc*8;
  for (int kt = 0; kt < 15; ++kt){
    uintx4 va0 = *(const uintx4a*)ap;
    uintx4 va1 = *(const uintx4a*)(ap + 32);
    uintx4 vb0 = *(const uintx4a*)bp;
    uintx4 vb1 = *(const uintx4a*)(bp + 32);
    ap += 64; bp += 64;
    *(uintx4a*)&sA[row*88 + kc*8]      = va0;
    *(uintx4a*)&sA[row*88 + 32 + kc*8] = va1;
    *(uintx4a*)&sB[row*88 + kc*8]      = vb0;
    *(uintx4a*)&sB[row*88 + 32 + kc*8] = vb1;
    __syncthreads();
    #pragma unroll
    for (int ks = 0; ks < 64; ks += 32){
      const shortx8 af0 = *(const shortx8a*)&sA[(mo      + m)*88 + ks + quad*8];
      const shortx8 af1 = *(const shortx8a*)&sA[(mo + 16 + m)*88 + ks + quad*8];
      const shortx8 bf0 = *(const shortx8a*)&sB[(no      + m)*88 + ks + quad*8];
      const shortx8 bf1 = *(const shortx8a*)&sB[(no + 16 + m)*88 + ks + quad*8];
      acc[0][0] = __builtin_amdgcn_mfma_f32_16x16x32_bf16(af0, bf0, acc[0][0], 0, 0, 0);
      acc[0][1] = __builtin_amdgcn_mfma_f32_16x16x32_bf16(af0, bf1, acc[0][1], 0, 0, 0);
      acc[1][0] = __builtin_amdgcn_mfma_f32_16x16x32_bf16(af1, bf0, acc[1][0], 0, 0, 0);
      acc[1][1] = __builtin_amdgcn_mfma_f32_16x16x32_bf16(af1, bf1, acc[1][1], 0, 0, 0);
    }
    __syncthreads();
  }
  #pragma unroll
  for (int mi = 0; mi < 2; ++mi)
    #pragma unroll
    for (int ni = 0; ni < 2; ++ni)
      #pragma unroll
      for (int r = 0; r < 4; ++r){
        int rr = m0 + mo + mi*16 + quad*4 + r;
        int cc = n0 + no + ni*16 + m;
        atomicAdd(&O[(size_t)rr*256 + cc], acc[mi][ni][r]);
      }
}

// ---------------------------------------------------------------------------
// Kernel 3: GCN aggregation + bias
// ---------------------------------------------------------------------------
__global__ void __launch_bounds__(256) gcn_agg(
    const float* __restrict__ xl, const int* __restrict__ ei,
    const float* __restrict__ ew, const float* __restrict__ gcn_b,
    float* __restrict__ Tpre){
  const int b = blockIdx.x, tid = threadIdx.x;
  __shared__ float sxl[15*256];
  __shared__ float s_deg[15], s_dinv[15], s_norm[71];
  __shared__ int   s_cnt[15], s_start[16], s_fill[15], s_srcl[71];
  if (tid < 15){ s_deg[tid] = 0.f; s_cnt[tid] = 0; s_fill[tid] = 0; }
  #pragma unroll
  for (int n = 0; n < 15; ++n)
    sxl[n*256 + tid] = xl[(size_t)(b*15 + n)*256 + tid];
  __syncthreads();
  int se = 0, de = 0; float we = 0.f;
  if (tid < 71){
    if (tid < 56){ se = ei[tid]; de = ei[56 + tid]; we = ew[tid]; }
    else         { se = tid - 56; de = tid - 56; we = 1.0f; }
    atomicAdd(&s_deg[de], we);
    atomicAdd(&s_cnt[de], 1);
  }
  __syncthreads();
  if (tid < 15) s_dinv[tid] = s_deg[tid] > 0.f ? rsqrtf(s_deg[tid]) : 0.f;
  if (tid == 0){
    int a = 0;
    for (int n = 0; n < 15; ++n){ s_start[n] = a; a += s_cnt[n]; }
    s_start[15] = a;
  }
  __syncthreads();
  if (tid < 71){
    float nrm = s_dinv[se]*we*s_dinv[de];
    int pos = s_start[de] + atomicAdd(&s_fill[de], 1);
    s_srcl[pos] = se; s_norm[pos] = nrm;
  }
  __syncthreads();
  const float gb = gcn_b[tid];
  for (int n = 0; n < 15; ++n){
    float acc = gb;
    const int e0 = s_start[n], e1 = s_start[n+1];
    for (int idx = e0; idx < e1; ++idx)
      acc += s_norm[idx]*sxl[s_srcl[idx]*256 + tid];
    Tpre[(size_t)(b*15 + n)*256 + tid] = acc;
  }
}

// ---------------------------------------------------------------------------
// Kernel 4: GraphNorm batch stats per (node, channel)
// ---------------------------------------------------------------------------
__global__ void __launch_bounds__(256) gn_stats(
    const float* __restrict__ Tpre, const float* __restrict__ gn_ms,
    const float* __restrict__ gn_w, float* __restrict__ moff, float* __restrict__ scal){
  const int n = blockIdx.x, c = threadIdx.x;
  float s = 0.f, s2 = 0.f;
  for (int b = 0; b < 128; ++b){
    float v = Tpre[(size_t)(b*15 + n)*256 + c];
    s += v; s2 += v*v;
  }
  const float mean = s*(1.f/128.f);
  const float mo = mean*gn_ms[c];
  float var = s2*(1.f/128.f) - 2.f*mo*mean + mo*mo;
  var = fmaxf(var, 0.f);
  moff[n*256 + c] = mo;
  scal[n*256 + c] = gn_w[c]*rsqrtf(var + 1e-5f);
}

// ---------------------------------------------------------------------------
// Kernel 5: normalize + lin1-add + ELU + node-mean pool + class head
// ---------------------------------------------------------------------------
__global__ void __launch_bounds__(256) finalize_k(
    const float* __restrict__ Tpre, const float* __restrict__ l1,
    const float* __restrict__ moff, const float* __restrict__ scal,
    const float* __restrict__ gn_b, const float* __restrict__ lin1_b,
    const float* __restrict__ out_w, const float* __restrict__ out_b,
    float* __restrict__ dout){
  const int b = blockIdx.x, tid = threadIdx.x;
  __shared__ float spool[256], spart[256];
  const float gnb = gn_b[tid], lb = lin1_b[tid];
  float acc = 0.f;
  #pragma unroll
  for (int n = 0; n < 15; ++n){
    float t = (Tpre[(size_t)(b*15 + n)*256 + tid] - moff[n*256 + tid])*scal[n*256 + tid]
              + gnb + l1[(size_t)(b*15 + n)*256 + tid] + lb;
    t = t > 0.f ? t : (__expf(t) - 1.f);   // ELU(alpha=1)
    acc += t;
  }
  const float pool = acc*(1.f/15.f);
  dout[b*256 + tid] = pool;
  spool[tid] = pool;
  __syncthreads();
  const int j = tid >> 4, q = tid & 15;
  float s = 0.f;
  for (int i = 0; i < 16; ++i){
    int cc = q + i*16;
    s += spool[cc]*out_w[j*256 + cc];
  }
  spart[tid] = s;
  __syncthreads();
  if (tid < 16){
    float tot = out_b[tid];
    #pragma unroll
    for (int i = 0; i < 16; ++i) tot += spart[tid*16 + i];
    dout[32768 + b*16 + tid] = tot;
  }
}

// ---------------------------------------------------------------------------
extern "C" void kernel_launch(void* const* d_in, const int* in_sizes, int n_in,
                              void* d_out, int out_size, void* d_ws, size_t ws_size,
                              hipStream_t stream){
  (void)in_sizes; (void)n_in; (void)out_size; (void)ws_size;
  const float* X    = (const float*)d_in[0];
  const int*   ei   = (const int*)d_in[1];
  const float* ew   = (const float*)d_in[2];
  const float* w1   = (const float*)d_in[3];
  const float* b1   = (const float*)d_in[4];
  const float* w2   = (const float*)d_in[5];
  const float* b2   = (const float*)d_in[6];
  const float* w3   = (const float*)d_in[7];
  const float* b3   = (const float*)d_in[8];
  const float* gw   = (const float*)d_in[9];
  const float* gb   = (const float*)d_in[10];
  const float* lw   = (const float*)d_in[11];
  const float* lb   = (const float*)d_in[12];
  const float* gnw  = (const float*)d_in[13];
  const float* gnb  = (const float*)d_in[14];
  const float* gnms = (const float*)d_in[15];
  const float* ow   = (const float*)d_in[16];
  const float* ob   = (const float*)d_in[17];

  char* ws = (char*)d_ws;
  u16*   h3p  = (u16*)(ws + 0);              //  7,372,800 B
  u16*   gwp  = (u16*)(ws + 7372800);        //    983,040 B
  u16*   Xb   = (u16*)(ws + 8355840);        //  7,372,800 B
  u16*   lwb  = (u16*)(ws + 15728640);       //    983,040 B
  float* xl   = (float*)(ws + 16711680);     //  1,966,080 B
  float* l1   = (float*)(ws + 18677760);     //  1,966,080 B (end 20,643,840)
  float* Tpre = (float*)(ws + 0);            // reuse h3p (dead after gemm)
  float* moff = (float*)(ws + 7372800);      // reuse gwp (dead after gemm)
  float* scal = (float*)(ws + 7388160);

  prep      <<<dim3(736),        dim3(256), 0, stream>>>(lw, lwb, gw, gwp,
                                                         (float*)(ws + 16711680));
  fused_conv<<<dim3(32, 8, 15),  dim3(512), 0, stream>>>(X, w1, b1, w2, b2, w3, b3,
                                                         h3p, Xb);
  gemm_nt   <<<dim3(30, 4, 4),   dim3(256), 0, stream>>>(Xb, lwb, l1, h3p, gwp, xl);
  gcn_agg   <<<dim3(128),        dim3(256), 0, stream>>>(xl, ei, ew, gb, Tpre);
  gn_stats  <<<dim3(15),         dim3(256), 0, stream>>>(Tpre, gnms, gnw, moff, scal);
  finalize_k<<<dim3(128),        dim3(256), 0, stream>>>(Tpre, l1, moff, scal,
                                                         gnb, lb, ow, ob, (float*)d_out);
}

// Round 9
// 205.471 us; speedup vs baseline: 1.4865x; 1.0677x over previous
//
#include <hip/hip_runtime.h>

typedef unsigned short u16;
typedef unsigned int   u32;

typedef short shortx8   __attribute__((ext_vector_type(8)));
typedef float floatx4   __attribute__((ext_vector_type(4)));
typedef float floatx16  __attribute__((ext_vector_type(16)));
typedef u32   uintx4    __attribute__((ext_vector_type(4)));

typedef u32     u32a     __attribute__((may_alias));
typedef uintx4  uintx4a  __attribute__((may_alias));
typedef shortx8 shortx8a __attribute__((may_alias));

// accurate round-to-nearest-even (weights)
__device__ __forceinline__ u16 f2bf(float f){
  union { float f; u32 i; } v; v.f = f;
  return (u16)((v.i + 0x7fffu + ((v.i >> 16) & 1u)) >> 16);
}
// fast round-half-up (scalar hot path; max 0.5 ulp)
__device__ __forceinline__ u16 f2bf_fast(float f){
  union { float f; u32 i; } v; v.f = f;
  return (u16)((v.i + 0x8000u) >> 16);
}
// pack two bf16 via v_perm (3 VALU ops) — fallback
__device__ __forceinline__ u32 pack2(float lo, float hi){
  union { float f; u32 i; } a, b; a.f = lo; b.f = hi;
  return __builtin_amdgcn_perm(b.i + 0x8000u, a.i + 0x8000u, 0x07060302u);
}
// packed f32->bf16 convert: 1 VALU op on gfx950 (v_cvt_pk_bf16_f32), RNE
__device__ __forceinline__ u32 cvtpk2(float lo, float hi){
#if __has_builtin(__builtin_amdgcn_cvt_pk_bf16_f32)
  auto pv = __builtin_amdgcn_cvt_pk_bf16_f32(lo, hi);
  if constexpr (sizeof(pv) == 4){
    u32 out; __builtin_memcpy(&out, &pv, 4); return out;
  } else {
    return pack2(lo, hi);
  }
#else
  return pack2(lo, hi);
#endif
}
__device__ __forceinline__ float lrelu(float v){ return fmaxf(v, 0.01f*v); }

// ---------------------------------------------------------------------------
// Kernel 1: fused conv1 (VALU) -> conv2 (MFMA 32x32x16) -> conv3 (MFMA
// 16x16x32). Per-wave LDS slots; __syncthreads at cross-lane LDS handoffs
// (compiler memory fence — round-5 lesson). Also: emits Xb (bf16 X) during
// staging, and absorbs prep (lin1_w cvt + gcn_w pad/cvt) distributed across
// the 3840 blocks — EXACTLY 256 elements each (983,040 total elements;
// round-8 crash: unbounded gid + bytes-vs-elements confusion -> OOB).
// grid (32 t-tiles, 8 b-groups, 15 nodes), block 512 (8 waves).
// ---------------------------------------------------------------------------
__global__ void __launch_bounds__(512, 4) fused_conv(
    const float* __restrict__ X,
    const float* __restrict__ w1, const float* __restrict__ b1,
    const float* __restrict__ w2, const float* __restrict__ b2,
    const float* __restrict__ w3, const float* __restrict__ b3,
    u16* __restrict__ h3p, u16* __restrict__ Xb,
    const float* __restrict__ lw, u16* __restrict__ lwb,
    const float* __restrict__ gw, u16* __restrict__ gwp){
  const int tid  = threadIdx.x;
  const int node = blockIdx.z;
  const int p    = blockIdx.x * 60;
  const int b0   = blockIdx.y * 16;

  __shared__ __attribute__((aligned(16))) u16 sH1[8*1632];  // per-wave [68][24]
  __shared__ __attribute__((aligned(16))) u16 sH2[8*2720];  // per-wave [68][40]
  __shared__ __attribute__((aligned(16))) u16 sW2f[2560];   // [tap][h][oc32][j8]
  __shared__ __attribute__((aligned(16))) u16 sW3f[160];    // [tap][ic32]
  __shared__ u16 sXb[16*76];                                // bf16 X window
  __shared__ float sW1[80], sB1[16], sB2[32];

  // ---- distributed prep: 256 elements per block, exact coverage ----
  {
    const int bid = blockIdx.x + 32*(blockIdx.y + 8*blockIdx.z);  // 0..3839
    if (tid < 256){
      int gid = bid*256 + tid;                 // 0..983039
      if (gid < 491520){
        lwb[gid] = f2bf(lw[gid]);              // lin1_w: 256*1920 elements
      } else {
        int g2 = gid - 491520;                 // 0..491519 (gwp elements)
        int row = g2 / 1920;                   // 0..255
        int col = g2 - row*1920;
        gwp[g2] = (col < 1908) ? f2bf(gw[row*1908 + col]) : (u16)0;
      }
    }
  }

  // ---- staging ----
  {
    const int bls = tid >> 5, i0 = tid & 31;
    const float* xrow = X  + (size_t)((b0 + bls)*15 + node)*1920;
    u16*        xbrow = Xb + (size_t)((b0 + bls)*15 + node)*1920;
    #pragma unroll
    for (int u = 0; u < 3; ++u){
      int i = i0 + 32*u;
      if (i < 76){
        int g = p + i;
        float xv = (i < 72 && g < 1920) ? xrow[g] : 0.f;
        u16 xb = f2bf_fast(xv);
        sXb[bls*76 + i] = xb;
        if (i < 60) xbrow[g] = xb;   // i<60 => g<1920 always
      }
    }
    // w2 into 32x32 A-frag order: idx = ((tap*2 + h)*32 + oc)*8 + j
    #pragma unroll
    for (int u = 0; u < 5; ++u){
      int d = tid + 512*u;
      int j = d & 7, oc = (d >> 3) & 31, h = (d >> 8) & 1, tap = d >> 9; // 0..4
      sW2f[d] = f2bf(w2[node*2560 + (oc*16 + h*8 + j)*5 + tap]);
    }
    if (tid < 160){
      int icc = tid / 5, tp = tid - 5*icc;
      sW3f[tp*32 + icc] = f2bf(w3[node*160 + tid]);
    }
    if (tid < 80) sW1[tid] = w1[node*80 + tid];
    if (tid < 16) sB1[tid] = b1[node*16 + tid];
    if (tid < 32) sB2[tid] = b2[node*32 + tid];
  }
  __syncthreads();

  const int w = tid >> 6, lane = tid & 63;
  const int m = lane & 15, quad = lane >> 4;
  const int t32 = lane & 31, h = lane >> 5;   // 32x32 roles

  // conv2 A-frags (32x32x16): A[m=oc=lane&31][k=h*8+j] = w2[oc][h*8+j][tap]
  shortx8 a2t[5];
  #pragma unroll
  for (int tap = 0; tap < 5; ++tap)
    a2t[tap] = *(const shortx8a*)&sW2f[((tap*2 + h)*32 + t32)*8];

  // conv2 bias per accumulator reg: row(oc) = (r&3) + 8*(r>>2) + 4*h
  float biasr[16];
  #pragma unroll
  for (int r = 0; r < 16; ++r)
    biasr[r] = sB2[(r&3) + 8*(r>>2) + 4*h];

  // conv3 A-frags (16x16x32): only row m=0 nonzero
  shortx8 a3[5];
  {
    const shortx8 zv = {0,0,0,0,0,0,0,0};
    #pragma unroll
    for (int tp = 0; tp < 5; ++tp){
      shortx8 t = *(const shortx8a*)&sW3f[tp*32 + quad*8];
      a3[tp] = (m == 0) ? t : zv;
    }
  }
  const float b3v = b3[node];

  u16* h1w = sH1 + w*1632;
  u16* h2w = sH2 + w*2720;
  // zero sH2 tail rows 64..67 (conv2 writes rows 0..63; conv3 reads to 67)
  for (int i = lane; i < 160; i += 64) h2w[2560 + i] = 0;

  // conv1 per-lane role: 8 ic-pairs x 8 t-chunks of 9
  const int c1ic = (lane & 7)*2, c1t0 = (lane >> 3)*9;
  float wa[5], wb[5];
  #pragma unroll
  for (int k = 0; k < 5; ++k){ wa[k] = sW1[c1ic*5 + k]; wb[k] = sW1[c1ic*5 + 5 + k]; }
  const float ba = sB1[c1ic], bbv = sB1[c1ic + 1];

  for (int bb = 0; bb < 2; ++bb){
    const int bl = w + bb*8;

    // ---- conv1 (VALU) for this wave's batch ----
    {
      const u16* xr = sXb + bl*76;
      union { u32 i; float f; } cv;
      float xw[5];
      #pragma unroll
      for (int k = 0; k < 4; ++k){ cv.i = ((u32)xr[c1t0+k]) << 16; xw[k] = cv.f; }
      #pragma unroll
      for (int i = 0; i < 9; ++i){
        const int t = c1t0 + i;
        cv.i = ((u32)xr[t + 4]) << 16; xw[4] = cv.f;
        float va = ba  + wa[0]*xw[0] + wa[1]*xw[1] + wa[2]*xw[2] + wa[3]*xw[3] + wa[4]*xw[4];
        float vb = bbv + wb[0]*xw[0] + wb[1]*xw[1] + wb[2]*xw[2] + wb[3]*xw[3] + wb[4]*xw[4];
        va = lrelu(va); vb = lrelu(vb);
        if (t < 68) *(u32a*)(h1w + t*24 + c1ic) = cvtpk2(va, vb);
        xw[0] = xw[1]; xw[1] = xw[2]; xw[2] = xw[3]; xw[3] = xw[4];
      }
    }
    __syncthreads();   // conv1 writes -> conv2 reads (cross-lane LDS handoff)

    // ---- conv2 (32x32x16): 2 t-tiles, 5 tap MFMAs each, bias in acc ----
    #pragma unroll
    for (int nt = 0; nt < 2; ++nt){
      const int t0 = nt*32;
      floatx16 acc;
      #pragma unroll
      for (int r = 0; r < 16; ++r) acc[r] = biasr[r];
      #pragma unroll
      for (int tap = 0; tap < 5; ++tap){
        shortx8 bfr = *(const shortx8a*)(h1w + (t0 + t32 + tap)*24 + h*8);
        acc = __builtin_amdgcn_mfma_f32_32x32x16_bf16(a2t[tap], bfr, acc, 0, 0, 0);
      }
      // D: col(t)=lane&31, row(oc)=(r&3)+8*(r>>2)+4*h; adjacent r-pairs = oc pairs
      u16* dst = h2w + (t0 + t32)*40;
      #pragma unroll
      for (int r = 0; r < 16; r += 2){
        float v0 = lrelu(acc[r]);
        float v1 = lrelu(acc[r+1]);
        const int oc0 = (r&3) + 8*(r>>2) + 4*h;
        *(u32a*)(dst + oc0) = cvtpk2(v0, v1);
      }
    }
    __syncthreads();   // conv2 writes -> conv3 reads (cross-lane LDS handoff)

    // ---- conv3 (16x16x32): 4 t-tiles, 5 tap MFMAs; result in D row 0 ----
    const int rg = (b0 + bl)*15 + node;
    #pragma unroll
    for (int nt = 0; nt < 4; ++nt){
      floatx4 acc3 = {0.f,0.f,0.f,0.f};
      if (lane < 16) acc3[0] = b3v;
      #pragma unroll
      for (int tp = 0; tp < 5; ++tp){
        shortx8 bfr = *(const shortx8a*)(h2w + (nt*16 + m + tp)*40 + quad*8);
        acc3 = __builtin_amdgcn_mfma_f32_16x16x32_bf16(a3[tp], bfr, acc3, 0, 0, 0);
      }
      const int tl = nt*16 + lane;
      if (lane < 16 && tl < 60){
        const int t3 = p + tl;
        float v = lrelu(acc3[0]);
        h3p[(size_t)rg*1920 + t3] = (t3 < 1908) ? f2bf_fast(v) : (u16)0;
      }
    }
  }
}

// ---------------------------------------------------------------------------
// Kernel 2: NT GEMM  O[1920][256] = A[1920][1920] * B[256][1920]^T (full K,
// plain stores). grid (30,4,2): z = job (0: Xb*lwb->l1, 1: h3p*gwp->xl).
// K-step 64; LDS stride 88 u16. Block (0,0,0) also zeroes the 30KB
// GraphNorm stats buffer (gS/gS2) consumed by gcn_agg/finalize.
// ---------------------------------------------------------------------------
__global__ void __launch_bounds__(256) gemm_nt(
    const u16* __restrict__ A0, const u16* __restrict__ B0, float* __restrict__ O0,
    const u16* __restrict__ A1, const u16* __restrict__ B1, float* __restrict__ O1,
    float* __restrict__ gZ){
  const int job = blockIdx.z;
  const u16* A; const u16* Bm; float* O;
  if (job == 0){ A = A0; Bm = B0; O = O0; } else { A = A1; Bm = B1; O = O1; }
  __shared__ __attribute__((aligned(16))) u16 sA[64*88];
  __shared__ __attribute__((aligned(16))) u16 sB[64*88];
  const int tid = threadIdx.x;
  if (blockIdx.x == 0 && blockIdx.y == 0 && job == 0){
    #pragma unroll
    for (int u = 0; u < 30; ++u) gZ[tid + 256*u] = 0.f;
  }
  const int m0 = blockIdx.x*64, n0 = blockIdx.y*64;
  const int row = tid >> 2, kc = tid & 3;
  const int w = tid >> 6, lane = tid & 63;
  const int m = lane & 15, quad = lane >> 4;
  const int mo = (w & 1)*32, no = (w >> 1)*32;
  floatx4 acc[2][2];
  #pragma unroll
  for (int i = 0; i < 2; ++i)
    #pragma unroll
    for (int j = 0; j < 2; ++j)
      #pragma unroll
      for (int r = 0; r < 4; ++r) acc[i][j][r] = 0.f;

  const u16* ap = A  + (size_t)(m0 + row)*1920 + kc*8;
  const u16* bp = Bm + (size_t)(n0 + row)*1920 + kc*8;
  for (int kt = 0; kt < 30; ++kt){
    uintx4 va0 = *(const uintx4a*)ap;
    uintx4 va1 = *(const uintx4a*)(ap + 32);
    uintx4 vb0 = *(const uintx4a*)bp;
    uintx4 vb1 = *(const uintx4a*)(bp + 32);
    ap += 64; bp += 64;
    *(uintx4a*)&sA[row*88 + kc*8]      = va0;
    *(uintx4a*)&sA[row*88 + 32 + kc*8] = va1;
    *(uintx4a*)&sB[row*88 + kc*8]      = vb0;
    *(uintx4a*)&sB[row*88 + 32 + kc*8] = vb1;
    __syncthreads();
    #pragma unroll
    for (int ks = 0; ks < 64; ks += 32){
      const shortx8 af0 = *(const shortx8a*)&sA[(mo      + m)*88 + ks + quad*8];
      const shortx8 af1 = *(const shortx8a*)&sA[(mo + 16 + m)*88 + ks + quad*8];
      const shortx8 bf0 = *(const shortx8a*)&sB[(no      + m)*88 + ks + quad*8];
      const shortx8 bf1 = *(const shortx8a*)&sB[(no + 16 + m)*88 + ks + quad*8];
      acc[0][0] = __builtin_amdgcn_mfma_f32_16x16x32_bf16(af0, bf0, acc[0][0], 0, 0, 0);
      acc[0][1] = __builtin_amdgcn_mfma_f32_16x16x32_bf16(af0, bf1, acc[0][1], 0, 0, 0);
      acc[1][0] = __builtin_amdgcn_mfma_f32_16x16x32_bf16(af1, bf0, acc[1][0], 0, 0, 0);
      acc[1][1] = __builtin_amdgcn_mfma_f32_16x16x32_bf16(af1, bf1, acc[1][1], 0, 0, 0);
    }
    __syncthreads();
  }
  #pragma unroll
  for (int mi = 0; mi < 2; ++mi)
    #pragma unroll
    for (int ni = 0; ni < 2; ++ni)
      #pragma unroll
      for (int r = 0; r < 4; ++r){
        int rr = m0 + mo + mi*16 + quad*4 + r;
        int cc = n0 + no + ni*16 + m;
        O[(size_t)rr*256 + cc] = acc[mi][ni][r];
      }
}

// ---------------------------------------------------------------------------
// Kernel 3: GCN aggregation + bias, plus per-(n,c) GraphNorm stat
// accumulation (atomicAdd of T and T^2 into gS/gS2, zeroed by gemm_nt).
// ---------------------------------------------------------------------------
__global__ void __launch_bounds__(256) gcn_agg(
    const float* __restrict__ xl, const int* __restrict__ ei,
    const float* __restrict__ ew, const float* __restrict__ gcn_b,
    float* __restrict__ Tpre, float* __restrict__ gS, float* __restrict__ gS2){
  const int b = blockIdx.x, tid = threadIdx.x;
  __shared__ float sxl[15*256];
  __shared__ float s_deg[15], s_dinv[15], s_norm[71];
  __shared__ int   s_cnt[15], s_start[16], s_fill[15], s_srcl[71];
  if (tid < 15){ s_deg[tid] = 0.f; s_cnt[tid] = 0; s_fill[tid] = 0; }
  #pragma unroll
  for (int n = 0; n < 15; ++n)
    sxl[n*256 + tid] = xl[(size_t)(b*15 + n)*256 + tid];
  __syncthreads();
  int se = 0, de = 0; float we = 0.f;
  if (tid < 71){
    if (tid < 56){ se = ei[tid]; de = ei[56 + tid]; we = ew[tid]; }
    else         { se = tid - 56; de = tid - 56; we = 1.0f; }
    atomicAdd(&s_deg[de], we);
    atomicAdd(&s_cnt[de], 1);
  }
  __syncthreads();
  if (tid < 15) s_dinv[tid] = s_deg[tid] > 0.f ? rsqrtf(s_deg[tid]) : 0.f;
  if (tid == 0){
    int a = 0;
    for (int n = 0; n < 15; ++n){ s_start[n] = a; a += s_cnt[n]; }
    s_start[15] = a;
  }
  __syncthreads();
  if (tid < 71){
    float nrm = s_dinv[se]*we*s_dinv[de];
    int pos = s_start[de] + atomicAdd(&s_fill[de], 1);
    s_srcl[pos] = se; s_norm[pos] = nrm;
  }
  __syncthreads();
  const float gb = gcn_b[tid];
  for (int n = 0; n < 15; ++n){
    float acc = gb;
    const int e0 = s_start[n], e1 = s_start[n+1];
    for (int idx = e0; idx < e1; ++idx)
      acc += s_norm[idx]*sxl[s_srcl[idx]*256 + tid];
    Tpre[(size_t)(b*15 + n)*256 + tid] = acc;
    atomicAdd(&gS [n*256 + tid], acc);
    atomicAdd(&gS2[n*256 + tid], acc*acc);
  }
}

// ---------------------------------------------------------------------------
// Kernel 4: GraphNorm (stats from gS/gS2) + lin1-add + ELU + pool + head
// ---------------------------------------------------------------------------
__global__ void __launch_bounds__(256) finalize_k(
    const float* __restrict__ Tpre, const float* __restrict__ l1,
    const float* __restrict__ gS, const float* __restrict__ gS2,
    const float* __restrict__ gn_ms, const float* __restrict__ gn_w,
    const float* __restrict__ gn_b, const float* __restrict__ lin1_b,
    const float* __restrict__ out_w, const float* __restrict__ out_b,
    float* __restrict__ dout){
  const int b = blockIdx.x, tid = threadIdx.x;
  __shared__ float spool[256], spart[256];
  const float gnb = gn_b[tid], lb = lin1_b[tid];
  const float gms = gn_ms[tid], gwc = gn_w[tid];
  float acc = 0.f;
  #pragma unroll
  for (int n = 0; n < 15; ++n){
    const float s  = gS [n*256 + tid];
    const float s2 = gS2[n*256 + tid];
    const float mean = s*(1.f/128.f);
    const float mo   = mean*gms;
    float var = s2*(1.f/128.f) - 2.f*mo*mean + mo*mo;
    var = fmaxf(var, 0.f);
    const float scal = gwc*rsqrtf(var + 1e-5f);
    float t = (Tpre[(size_t)(b*15 + n)*256 + tid] - mo)*scal
              + gnb + l1[(size_t)(b*15 + n)*256 + tid] + lb;
    t = t > 0.f ? t : (__expf(t) - 1.f);   // ELU(alpha=1)
    acc += t;
  }
  const float pool = acc*(1.f/15.f);
  dout[b*256 + tid] = pool;
  spool[tid] = pool;
  __syncthreads();
  const int j = tid >> 4, q = tid & 15;
  float s = 0.f;
  for (int i = 0; i < 16; ++i){
    int cc = q + i*16;
    s += spool[cc]*out_w[j*256 + cc];
  }
  spart[tid] = s;
  __syncthreads();
  if (tid < 16){
    float tot = out_b[tid];
    #pragma unroll
    for (int i = 0; i < 16; ++i) tot += spart[tid*16 + i];
    dout[32768 + b*16 + tid] = tot;
  }
}

// ---------------------------------------------------------------------------
extern "C" void kernel_launch(void* const* d_in, const int* in_sizes, int n_in,
                              void* d_out, int out_size, void* d_ws, size_t ws_size,
                              hipStream_t stream){
  (void)in_sizes; (void)n_in; (void)out_size; (void)ws_size;
  const float* X    = (const float*)d_in[0];
  const int*   ei   = (const int*)d_in[1];
  const float* ew   = (const float*)d_in[2];
  const float* w1   = (const float*)d_in[3];
  const float* b1   = (const float*)d_in[4];
  const float* w2   = (const float*)d_in[5];
  const float* b2   = (const float*)d_in[6];
  const float* w3   = (const float*)d_in[7];
  const float* b3   = (const float*)d_in[8];
  const float* gw   = (const float*)d_in[9];
  const float* gb   = (const float*)d_in[10];
  const float* lw   = (const float*)d_in[11];
  const float* lb   = (const float*)d_in[12];
  const float* gnw  = (const float*)d_in[13];
  const float* gnb  = (const float*)d_in[14];
  const float* gnms = (const float*)d_in[15];
  const float* ow   = (const float*)d_in[16];
  const float* ob   = (const float*)d_in[17];

  char* ws = (char*)d_ws;
  u16*   h3p  = (u16*)(ws + 0);              //  7,372,800 B
  u16*   gwp  = (u16*)(ws + 7372800);        //    983,040 B (491,520 u16)
  u16*   Xb   = (u16*)(ws + 8355840);        //  7,372,800 B
  u16*   lwb  = (u16*)(ws + 15728640);       //    983,040 B (491,520 u16)
  float* xl   = (float*)(ws + 16711680);     //  1,966,080 B
  float* l1   = (float*)(ws + 18677760);     //  1,966,080 B
  float* gS   = (float*)(ws + 20643840);     //     15,360 B
  float* gS2  = (float*)(ws + 20659200);     //     15,360 B (end 20,674,560)
  float* Tpre = (float*)(ws + 0);            // reuse h3p (dead after gemm)

  fused_conv<<<dim3(32, 8, 15), dim3(512), 0, stream>>>(X, w1, b1, w2, b2, w3, b3,
                                                        h3p, Xb, lw, lwb, gw, gwp);
  gemm_nt   <<<dim3(30, 4, 2),  dim3(256), 0, stream>>>(Xb, lwb, l1, h3p, gwp, xl, gS);
  gcn_agg   <<<dim3(128),       dim3(256), 0, stream>>>(xl, ei, ew, gb, Tpre, gS, gS2);
  finalize_k<<<dim3(128),       dim3(256), 0, stream>>>(Tpre, l1, gS, gS2,
                                                        gnms, gnw, gnb, lb, ow, ob,
                                                        (float*)d_out);
}